// Round 14
// baseline (174.531 us; speedup 1.0000x reference)
//
#include <hip/hip_runtime.h>
#include <hip/hip_bf16.h>
#include <math.h>

#define BB 64
#define NN 256
#define D_VIS 2048
#define D_LBL 512
#define HH 8
#define FF 256
#define DG 2048   // D_GAT = H*F
#define DE 512    // D_EMB
#define ALPHA 0.2f
#define PSTRIDE 264  // Pl row stride in shorts (256 + 8 pad)
#define NSPLIT 4     // k_pool n-split partials

using bf16 = __hip_bfloat16;
using short8 = __attribute__((ext_vector_type(8))) short;
using f32x4  = __attribute__((ext_vector_type(4))) float;
__device__ __forceinline__ float b2f(bf16 x) { return __bfloat162float(x); }
__device__ __forceinline__ unsigned short f2bs(float x) {
    bf16 h = __float2bfloat16(x);
    unsigned short u;
    __builtin_memcpy(&u, &h, 2);
    return u;
}
__device__ __forceinline__ float bs2f(unsigned short u) {
    unsigned int x = (unsigned int)u << 16;
    float f;
    __builtin_memcpy(&f, &x, 4);
    return f;
}

// ---------------- fused Wh GEMM + adj-bitmask builder (round-5 config).
// grid (32, 9), 256 thr. Register-prefetch double-buffered staging:
// one barrier per K-step; next tile's global loads in flight across MFMA.
__global__ void __launch_bounds__(256) k_wh(const float* __restrict__ labels,
                                            const float* __restrict__ visual,
                                            const float* __restrict__ Wg,
                                            unsigned short* __restrict__ WhLbT,
                                            float* __restrict__ WhVz,
                                            const float* __restrict__ aSrc,
                                            const float* __restrict__ aDst,
                                            float* __restrict__ srcLp,
                                            float* __restrict__ dstLp,
                                            float* __restrict__ srcVp,
                                            float* __restrict__ dstVp,
                                            const float* __restrict__ adj,
                                            unsigned short* __restrict__ abits) {
    const int t = threadIdx.x;
    const int y = blockIdx.y;
    if (y == 8) {
        if (t < 128) {
            const int r = t >> 4, s = t & 15;
            const int i = blockIdx.x * 8 + r;
            unsigned int bits = 0;
#pragma unroll
            for (int jj = 0; jj < 8; ++jj) {
                const float2 av = *(const float2*)(adj + (size_t)i * NN + 2 * s + 32 * jj);
                bits |= (av.x > 0.f ? 1u : 0u) << (2 * jj);
                bits |= (av.y > 0.f ? 1u : 0u) << (2 * jj + 1);
            }
            abits[i * 16 + s] = (unsigned short)bits;
        }
        return;
    }

    __shared__ unsigned short As[2][64][72];  // 18.4 KB
    __shared__ unsigned short Bs[2][64][72];  // 18.4 KB
    const int w = t >> 6;
    const int lane = t & 63;
    const int l15 = lane & 15, quad = lane >> 4;
    const int n0 = blockIdx.x * 64;
    const int p2 = blockIdx.x & 3;     // quarter of head's 256 cols
    const bool isL = (y < 4);
    const int m0  = isL ? y * 64 : 0;
    const int z   = isL ? 0 : (y - 4);
    const int kb0 = z * 512;
    const float* A = isL ? labels : visual;
    const int lda  = isL ? D_LBL : D_VIS;
    const float* Wb = Wg + (isL ? 0 : (size_t)D_LBL * DG);

    f32x4 acc[4];
#pragma unroll
    for (int mi = 0; mi < 4; ++mi) acc[mi] = (f32x4){0.f, 0.f, 0.f, 0.f};

    float4 ra[4], rb[4];
    auto load_tile = [&](int kc) {
        const int kb = kb0 + kc * 64;
#pragma unroll
        for (int p = 0; p < 4; ++p) {
            const int idx = t + 256 * p;
            const int r = idx >> 4, q4 = idx & 15;
            ra[p] = *(const float4*)(A + (size_t)(m0 + r) * lda + kb + 4 * q4);
        }
#pragma unroll
        for (int p = 0; p < 4; ++p) {
            const int kk = (t >> 4) + 16 * p;
            const int c4 = (t & 15) * 4;
            rb[p] = *(const float4*)(Wb + (size_t)(kb + kk) * DG + n0 + c4);
        }
    };
    auto store_tile = [&](int buf) {
#pragma unroll
        for (int p = 0; p < 4; ++p) {
            const int idx = t + 256 * p;
            const int r = idx >> 4, q4 = idx & 15;
            unsigned short s4[4] = {f2bs(ra[p].x), f2bs(ra[p].y), f2bs(ra[p].z), f2bs(ra[p].w)};
            __builtin_memcpy(&As[buf][r][4 * q4], s4, 8);
        }
#pragma unroll
        for (int p = 0; p < 4; ++p) {
            const int kk = (t >> 4) + 16 * p;
            const int c4 = (t & 15) * 4;
            Bs[buf][c4 + 0][kk] = f2bs(rb[p].x);
            Bs[buf][c4 + 1][kk] = f2bs(rb[p].y);
            Bs[buf][c4 + 2][kk] = f2bs(rb[p].z);
            Bs[buf][c4 + 3][kk] = f2bs(rb[p].w);
        }
    };

    load_tile(0);
    store_tile(0);
    __syncthreads();
    for (int kc = 0; kc < 8; ++kc) {
        const int cur = kc & 1;
        if (kc < 7) load_tile(kc + 1);   // loads in flight across MFMA
#pragma unroll
        for (int ks = 0; ks < 2; ++ks) {
            const short8 bf = *(const short8*)&Bs[cur][w * 16 + l15][ks * 32 + quad * 8];
#pragma unroll
            for (int mi = 0; mi < 4; ++mi) {
                const short8 af = *(const short8*)&As[cur][mi * 16 + l15][ks * 32 + quad * 8];
                acc[mi] = __builtin_amdgcn_mfma_f32_16x16x32_bf16(af, bf, acc[mi], 0, 0, 0);
            }
        }
        if (kc < 7) store_tile(cur ^ 1);
        __syncthreads();   // single barrier per K-step
    }
    const int col = n0 + w * 16 + l15;
    const int h = col >> 8;
    const float as = aSrc[col], ad = aDst[col];
    if (isL) {
#pragma unroll
        for (int mi = 0; mi < 4; ++mi) {
            unsigned short s4[4];
#pragma unroll
            for (int r = 0; r < 4; ++r) s4[r] = f2bs(acc[mi][r]);
            __builtin_memcpy(&WhLbT[(size_t)col * NN + m0 + mi * 16 + quad * 4], s4, 8);
        }
#pragma unroll
        for (int mi = 0; mi < 4; ++mi)
#pragma unroll
            for (int r = 0; r < 4; ++r) {
                float sv = acc[mi][r] * as;
                float dv = acc[mi][r] * ad;
#pragma unroll
                for (int off = 1; off < 16; off <<= 1) {
                    sv += __shfl_xor(sv, off);
                    dv += __shfl_xor(dv, off);
                }
                if (l15 == 0) {
                    const int row = m0 + mi * 16 + quad * 4 + r;
                    srcLp[(p2 * NN + row) * HH + h] = sv;  // unique writer
                    dstLp[(p2 * NN + row) * HH + h] = dv;
                }
            }
    } else {
        float* Wv = WhVz + (size_t)z * BB * DG;
#pragma unroll
        for (int mi = 0; mi < 4; ++mi)
#pragma unroll
            for (int r = 0; r < 4; ++r)
                Wv[(size_t)(mi * 16 + quad * 4 + r) * DG + col] = acc[mi][r];
        const int pv = p2 * 4 + z;
#pragma unroll
        for (int mi = 0; mi < 4; ++mi)
#pragma unroll
            for (int r = 0; r < 4; ++r) {
                float sv = acc[mi][r] * as;
                float dv = acc[mi][r] * ad;
#pragma unroll
                for (int off = 1; off < 16; off <<= 1) {
                    sv += __shfl_xor(sv, off);
                    dv += __shfl_xor(dv, off);
                }
                if (l15 == 0) {
                    const int row = mi * 16 + quad * 4 + r;
                    srcVp[(pv * BB + row) * HH + h] = sv;  // unique writer
                    dstVp[(pv * BB + row) * HH + h] = dv;
                }
            }
    }
}

// ---------------- MFMA GAT v8: v6 + swapped-operand MFMA (out^T tile layout).
// mfma(Wh_frag, P_frag) -> D[m=d][n=i]: thread holds 4 consecutive d-cols
// per reg quad -> 8B packed stores (was 32x2B), quad-shfl pool dot (8 shfl,
// was 64), 4 inv reads (was 16). Same LDS/global loads as v6.
__global__ void __launch_bounds__(512, 4) k_gat(const unsigned short* __restrict__ WhLbT,
                                                const float* __restrict__ WhVz,
                                                const float* __restrict__ srcLp,
                                                const float* __restrict__ dstLp,
                                                const float* __restrict__ srcVp,
                                                const float* __restrict__ dstVp,
                                                const unsigned short* __restrict__ abits,
                                                const float* __restrict__ pool_q,
                                                bf16* __restrict__ outb,
                                                float* __restrict__ ps_p) {
    const int bid = blockIdx.x;
    const int h = bid & 7;
    const int b = bid >> 3;
    const int t = threadIdx.x;
    const int w = t >> 6;
    const int lane = t & 63;
    const int l15 = lane & 15, quad = lane >> 4;

    __shared__ __align__(16) unsigned short Pl[64][PSTRIDE]; // 33.8 KB
    __shared__ __align__(16) float dls2[2 * NN];             // 2 KB
    __shared__ float slsA[NN], slsC[NN];                     // 2 KB
    __shared__ float inv[64];
    __shared__ float psl[8][64];                             // 2 KB

    // ---- phase 0 (hoisted: once per (b,h), covers all 4 it-tiles)
    if (t < NN) {
        float dl = 0.f, sl = 0.f;
#pragma unroll
        for (int p = 0; p < 4; ++p) {
            dl += dstLp[(p * NN + t) * HH + h];
            sl += srcLp[(p * NN + t) * HH + h];
        }
        dls2[2 * t]     = __expf(dl);
        dls2[2 * t + 1] = __expf(ALPHA * dl);
        float c = 0.f;
#pragma unroll
        for (int p = 0; p < 16; ++p)
            c += srcVp[(p * BB + b) * HH + h] + dstVp[(p * BB + b) * HH + h];
        const float u = c + sl;
        slsA[t] = __expf(u);
        slsC[t] = __expf(ALPHA * u);
    }
    const int n0 = w * 32;
    // wv8/pq8: per-thread d = h*FF + n0 + (j>>2)*16 + quad*4 + (j&3)
    float wv8[8], pq8[8];
#pragma unroll
    for (int j = 0; j < 8; ++j) {
        const int d = h * FF + n0 + (j >> 2) * 16 + quad * 4 + (j & 3);
        float a0 = 0.f;
#pragma unroll
        for (int z = 0; z < 4; ++z)
            a0 += WhVz[(size_t)z * BB * DG + (size_t)b * DG + d];
        wv8[j] = a0;
        pq8[j] = pool_q[d];
    }
    const unsigned short* wb = WhLbT + (size_t)(h * FF + n0 + l15) * NN + quad * 8;
    __syncthreads();

    for (int it = 0; it < 4; ++it) {
        const int i0 = it * 64;

        // ---- phase 1: masked exp via max identity (adj from 8KB bitmask)
        {
            const int g = lane >> 4, s = lane & 15;
#pragma unroll
            for (int rr = 0; rr < 2; ++rr) {
                const int iloc = w * 8 + rr * 4 + g;
                const int i = i0 + iloc;
                const unsigned int mb = abits[i * 16 + s];
                const float Ai = slsA[i], Ci = slsC[i];
                float pr[16];
                float sum = 0.f;
#pragma unroll
                for (int jj = 0; jj < 8; ++jj) {
                    const int j0 = 2 * s + 32 * jj;
                    const float4 bd = *(const float4*)&dls2[2 * j0];
                    float p0 = fmaxf(Ai * bd.x, Ci * bd.y);
                    float p1 = fmaxf(Ai * bd.z, Ci * bd.w);
                    p0 = (mb & (1u << (2 * jj)))     ? p0 : 0.f;
                    p1 = (mb & (1u << (2 * jj + 1))) ? p1 : 0.f;
                    pr[2 * jj] = p0; pr[2 * jj + 1] = p1;
                    sum += p0 + p1;
                }
#pragma unroll
                for (int off = 1; off < 16; off <<= 1) sum += __shfl_xor(sum, off);
                if (s == 0) inv[iloc] = 1.0f / sum;
#pragma unroll
                for (int jj = 0; jj < 8; ++jj) {
                    const unsigned int pk =
                        ((unsigned int)f2bs(pr[2 * jj + 1]) << 16) | f2bs(pr[2 * jj]);
                    *(unsigned int*)&Pl[iloc][2 * s + 32 * jj] = pk;
                }
            }
        }
        __syncthreads();

        // ---- phase 2 (swapped): acc[mi][ni] = Wh_tile(ni) . P^T_tile(mi)
        // D[m = d-local (quad*4+r), n = i-local (l15)] — same loads as v6.
        f32x4 acc[4][2];
#pragma unroll
        for (int mi = 0; mi < 4; ++mi)
#pragma unroll
            for (int ni = 0; ni < 2; ++ni) acc[mi][ni] = (f32x4){0.f, 0.f, 0.f, 0.f};

        short8 bc0 = *(const short8*)(wb);
        short8 bc1 = *(const short8*)(wb + (size_t)16 * NN);
#pragma unroll
        for (int kc = 0; kc < 8; ++kc) {
            short8 bn0, bn1;
            if (kc < 7) {
                bn0 = *(const short8*)(wb + (kc + 1) * 32);
                bn1 = *(const short8*)(wb + (size_t)16 * NN + (kc + 1) * 32);
            }
            short8 a[4];
#pragma unroll
            for (int mi = 0; mi < 4; ++mi)
                a[mi] = *(const short8*)&Pl[mi * 16 + l15][kc * 32 + quad * 8];
#pragma unroll
            for (int mi = 0; mi < 4; ++mi)
                acc[mi][0] = __builtin_amdgcn_mfma_f32_16x16x32_bf16(bc0, a[mi], acc[mi][0], 0, 0, 0);
#pragma unroll
            for (int mi = 0; mi < 4; ++mi)
                acc[mi][1] = __builtin_amdgcn_mfma_f32_16x16x32_bf16(bc1, a[mi], acc[mi][1], 0, 0, 0);
            bc0 = bn0; bc1 = bn1;
        }

        // ---- epilogue (transposed): row i = i0+mi*16+l15; thread owns
        // d = n0 + ni*16 + quad*4 + r -> 8B packed stores, quad-shfl dot.
#pragma unroll
        for (int mi = 0; mi < 4; ++mi) {
            const int i = i0 + mi * 16 + l15;
            const float ivr = inv[mi * 16 + l15];
            bf16* orow = outb + (size_t)(b * NN + i) * DG + h * FF + n0;
            float dotp = 0.f;
#pragma unroll
            for (int ni = 0; ni < 2; ++ni) {
                unsigned short us[4];
#pragma unroll
                for (int r = 0; r < 4; ++r) {
                    float x = fmaf(acc[mi][ni][r], ivr, wv8[ni * 4 + r]);
                    x = x > 0.f ? x : (__expf(x) - 1.0f);
                    us[r] = f2bs(x);
                    dotp = fmaf(x, pq8[ni * 4 + r], dotp);
                }
                __builtin_memcpy(orow + ni * 16 + quad * 4, us, 8);
            }
            dotp += __shfl_xor(dotp, 16);
            dotp += __shfl_xor(dotp, 32);
            if (quad == 0) psl[w][mi * 16 + l15] = dotp;
        }
        __syncthreads();  // psl ready; Pl consumers done (safe to rewrite next it)
        if (t < 64) {
            float s = 0.f;
#pragma unroll
            for (int ww = 0; ww < 8; ++ww) s += psl[ww][t];
            ps_p[((size_t)h * BB + b) * NN + i0 + t] = s;
        }
        // next-it psl/Pl writes are gated by the phase-1 barrier, which the
        // reducing wave reaches only after this store.
    }
}

// ---------------- k_pool v3 (round-5): n-split partials, full-GPU streaming.
// grid (4 dt, 64 b, 4 ns), 256 thr; thread owns TWO consecutive d cols,
// n-range 64 per block -> 1024 blocks. Partials summed in k_mgemm.
__global__ void __launch_bounds__(256) k_pool(const bf16* __restrict__ outb,
                                              const float* __restrict__ ps_p,
                                              float* __restrict__ pooled_p,
                                              const float* __restrict__ fcb,
                                              float* __restrict__ out) {
    const int dt = blockIdx.x;  // 0..3
    const int b  = blockIdx.y;  // 0..63
    const int ns = blockIdx.z;  // 0..3
    const int t  = threadIdx.x;
    if (dt == 0 && ns == 0) {
        out[b * DE + t]       = fcb[t];
        out[b * DE + 256 + t] = fcb[256 + t];
    }
    __shared__ float wsm[NN];
    __shared__ float redm[4];
    __shared__ float reds[4];
    float v = 0.f;
#pragma unroll
    for (int s = 0; s < 8; ++s)
        v += ps_p[((size_t)s * BB + b) * NN + t];
    float m = v;
#pragma unroll
    for (int off = 32; off; off >>= 1) m = fmaxf(m, __shfl_xor(m, off));
    if ((t & 63) == 0) redm[t >> 6] = m;
    __syncthreads();
    m = fmaxf(fmaxf(redm[0], redm[1]), fmaxf(redm[2], redm[3]));
    const float e = __expf(v - m);
    float s = e;
#pragma unroll
    for (int off = 32; off; off >>= 1) s += __shfl_xor(s, off);
    if ((t & 63) == 0) reds[t >> 6] = s;
    __syncthreads();
    s = reds[0] + reds[1] + reds[2] + reds[3];
    wsm[t] = e / s;
    __syncthreads();
    const int d0 = dt * 512 + t * 2;
    const int nb = ns * 64;
    float a0 = 0.f, a1 = 0.f;
    const bf16* base = outb + (size_t)b * NN * DG + d0;
#pragma unroll 8
    for (int n = 0; n < 64; ++n) {
        unsigned int q = *(const unsigned int*)(base + (size_t)(nb + n) * DG);
        const float wn = wsm[nb + n];
        a0 = fmaf(wn, bs2f((unsigned short)(q & 0xffff)), a0);
        a1 = fmaf(wn, bs2f((unsigned short)(q >> 16)), a1);
    }
    float2 r2 = {a0, a1};
    *(float2*)(pooled_p + ((size_t)(ns * BB + b)) * DG + d0) = r2;
}

// ---------------- fc GEMM: A = sum of NSPLIT pooled partials; atomic ksplit
__global__ void __launch_bounds__(256) k_mgemm(const float* __restrict__ Ap,
                                               const float* __restrict__ W, int ldw,
                                               float* __restrict__ C, int ldc,
                                               int kSlice, int kIters) {
    __shared__ unsigned short As[32][72];
    __shared__ unsigned short Bs[64][72];
    const int t = threadIdx.x;
    const int w = t >> 6;
    const int lane = t & 63;
    const int l15 = lane & 15, quad = lane >> 4;
    const int n0 = blockIdx.x * 64;
    const int m0 = blockIdx.y * 32;
    const int kb0 = blockIdx.z * kSlice;
    f32x4 acc[2];
    acc[0] = (f32x4){0.f, 0.f, 0.f, 0.f};
    acc[1] = (f32x4){0.f, 0.f, 0.f, 0.f};
    for (int kc = 0; kc < kIters; ++kc) {
        const int kb = kb0 + kc * 64;
#pragma unroll
        for (int p = 0; p < 2; ++p) {
            const int idx = t + 256 * p;
            const int r = idx >> 4, q4 = idx & 15;
            const float* ap = Ap + (size_t)(m0 + r) * DG + kb + 4 * q4;
            const float4 v0 = *(const float4*)(ap);
            const float4 v1 = *(const float4*)(ap + (size_t)BB * DG);
            const float4 v2 = *(const float4*)(ap + (size_t)2 * BB * DG);
            const float4 v3 = *(const float4*)(ap + (size_t)3 * BB * DG);
            const float vx = v0.x + v1.x + v2.x + v3.x;
            const float vy = v0.y + v1.y + v2.y + v3.y;
            const float vz = v0.z + v1.z + v2.z + v3.z;
            const float vw = v0.w + v1.w + v2.w + v3.w;
            unsigned short s4[4] = {f2bs(vx), f2bs(vy), f2bs(vz), f2bs(vw)};
            __builtin_memcpy(&As[r][4 * q4], s4, 8);
        }
#pragma unroll
        for (int p = 0; p < 4; ++p) {
            const int kk = (t >> 4) + 16 * p;
            const int c4 = (t & 15) * 4;
            const float4 v = *(const float4*)(W + (size_t)(kb + kk) * ldw + n0 + c4);
            Bs[c4 + 0][kk] = f2bs(v.x);
            Bs[c4 + 1][kk] = f2bs(v.y);
            Bs[c4 + 2][kk] = f2bs(v.z);
            Bs[c4 + 3][kk] = f2bs(v.w);
        }
        __syncthreads();
#pragma unroll
        for (int ks = 0; ks < 2; ++ks) {
            const short8 bf = *(const short8*)&Bs[w * 16 + l15][ks * 32 + quad * 8];
#pragma unroll
            for (int mi = 0; mi < 2; ++mi) {
                const short8 af = *(const short8*)&As[mi * 16 + l15][ks * 32 + quad * 8];
                acc[mi] = __builtin_amdgcn_mfma_f32_16x16x32_bf16(af, bf, acc[mi], 0, 0, 0);
            }
        }
        __syncthreads();
    }
    const int col = n0 + w * 16 + l15;
#pragma unroll
    for (int mi = 0; mi < 2; ++mi)
#pragma unroll
        for (int r = 0; r < 4; ++r)
            atomicAdd(&C[(size_t)(m0 + mi * 16 + quad * 4 + r) * ldc + col], acc[mi][r]);
}

extern "C" void kernel_launch(void* const* d_in, const int* in_sizes, int n_in,
                              void* d_out, int out_size, void* d_ws, size_t ws_size,
                              hipStream_t stream) {
    (void)in_sizes; (void)n_in; (void)out_size; (void)ws_size;
    const float* visual = (const float*)d_in[0];
    const float* labels = (const float*)d_in[1];
    const float* adj    = (const float*)d_in[2];
    const float* Wg     = (const float*)d_in[3];
    const float* a_src  = (const float*)d_in[4];
    const float* a_dst  = (const float*)d_in[5];
    const float* pool_q = (const float*)d_in[6];
    const float* fcW    = (const float*)d_in[7];
    const float* fcb    = (const float*)d_in[8];
    float* out = (float*)d_out;

    float* ws_f     = (float*)d_ws;
    float* WhVz     = ws_f;                       // 4*64*2048
    float* srcLp    = WhVz + 4 * BB * DG;         // 4*256*8
    float* dstLp    = srcLp + 4 * NN * HH;        // 4*256*8
    float* srcVp    = dstLp + 4 * NN * HH;        // 16*64*8
    float* dstVp    = srcVp + 16 * BB * HH;       // 16*64*8
    float* ps_p     = dstVp + 16 * BB * HH;       // 8*64*256 (h-slices only)
    float* pooled_p = ps_p + 8 * BB * NN;         // 4*64*2048 (ns partials)
    bf16*  outb     = (bf16*)(pooled_p + NSPLIT * BB * DG);  // 64*256*2048 bf16
    unsigned short* WhLbT = (unsigned short*)(outb + (size_t)BB * NN * DG); // 2048*256
    unsigned short* abits = WhLbT + (size_t)DG * NN;  // 256*16 ushort (8KB)

    k_wh<<<dim3(DG / 64, 9), 256, 0, stream>>>(labels, visual, Wg, WhLbT, WhVz,
                                               a_src, a_dst, srcLp, dstLp, srcVp, dstVp,
                                               adj, abits);

    k_gat<<<BB * HH, 512, 0, stream>>>(WhLbT, WhVz, srcLp, dstLp, srcVp, dstVp,
                                       abits, pool_q, outb, ps_p);

    k_pool<<<dim3(4, BB, NSPLIT), 256, 0, stream>>>(outb, ps_p, pooled_p, fcb, out);

    k_mgemm<<<dim3(DE / 64, BB / 32, 16), 256, 0, stream>>>(
        pooled_p, fcW, DE, out, DE, 128, 2);
}

// Round 15
// 162.910 us; speedup vs baseline: 1.0713x; 1.0713x over previous
//
#include <hip/hip_runtime.h>
#include <hip/hip_bf16.h>
#include <math.h>

#define BB 64
#define NN 256
#define D_VIS 2048
#define D_LBL 512
#define HH 8
#define FF 256
#define DG 2048   // D_GAT = H*F
#define DE 512    // D_EMB
#define ALPHA 0.2f
#define PSTRIDE 264  // Pl row stride in shorts (256 + 8 pad)
#define NSPLIT 4     // k_pool n-split partials

using bf16 = __hip_bfloat16;
using short8 = __attribute__((ext_vector_type(8))) short;
using f32x4  = __attribute__((ext_vector_type(4))) float;
__device__ __forceinline__ float b2f(bf16 x) { return __bfloat162float(x); }
__device__ __forceinline__ unsigned short f2bs(float x) {
    bf16 h = __float2bfloat16(x);
    unsigned short u;
    __builtin_memcpy(&u, &h, 2);
    return u;
}
__device__ __forceinline__ float bs2f(unsigned short u) {
    unsigned int x = (unsigned int)u << 16;
    float f;
    __builtin_memcpy(&f, &x, 4);
    return f;
}

// ---------------- fused Wh GEMM + adj-bitmask builder (round-5 config).
// grid (32, 9), 256 thr. Register-prefetch double-buffered staging:
// one barrier per K-step; next tile's global loads in flight across MFMA.
__global__ void __launch_bounds__(256) k_wh(const float* __restrict__ labels,
                                            const float* __restrict__ visual,
                                            const float* __restrict__ Wg,
                                            unsigned short* __restrict__ WhLbT,
                                            float* __restrict__ WhVz,
                                            const float* __restrict__ aSrc,
                                            const float* __restrict__ aDst,
                                            float* __restrict__ srcLp,
                                            float* __restrict__ dstLp,
                                            float* __restrict__ srcVp,
                                            float* __restrict__ dstVp,
                                            const float* __restrict__ adj,
                                            unsigned short* __restrict__ abits) {
    const int t = threadIdx.x;
    const int y = blockIdx.y;
    if (y == 8) {
        if (t < 128) {
            const int r = t >> 4, s = t & 15;
            const int i = blockIdx.x * 8 + r;
            unsigned int bits = 0;
#pragma unroll
            for (int jj = 0; jj < 8; ++jj) {
                const float2 av = *(const float2*)(adj + (size_t)i * NN + 2 * s + 32 * jj);
                bits |= (av.x > 0.f ? 1u : 0u) << (2 * jj);
                bits |= (av.y > 0.f ? 1u : 0u) << (2 * jj + 1);
            }
            abits[i * 16 + s] = (unsigned short)bits;
        }
        return;
    }

    __shared__ unsigned short As[2][64][72];  // 18.4 KB
    __shared__ unsigned short Bs[2][64][72];  // 18.4 KB
    const int w = t >> 6;
    const int lane = t & 63;
    const int l15 = lane & 15, quad = lane >> 4;
    const int n0 = blockIdx.x * 64;
    const int p2 = blockIdx.x & 3;     // quarter of head's 256 cols
    const bool isL = (y < 4);
    const int m0  = isL ? y * 64 : 0;
    const int z   = isL ? 0 : (y - 4);
    const int kb0 = z * 512;
    const float* A = isL ? labels : visual;
    const int lda  = isL ? D_LBL : D_VIS;
    const float* Wb = Wg + (isL ? 0 : (size_t)D_LBL * DG);

    f32x4 acc[4];
#pragma unroll
    for (int mi = 0; mi < 4; ++mi) acc[mi] = (f32x4){0.f, 0.f, 0.f, 0.f};

    float4 ra[4], rb[4];
    auto load_tile = [&](int kc) {
        const int kb = kb0 + kc * 64;
#pragma unroll
        for (int p = 0; p < 4; ++p) {
            const int idx = t + 256 * p;
            const int r = idx >> 4, q4 = idx & 15;
            ra[p] = *(const float4*)(A + (size_t)(m0 + r) * lda + kb + 4 * q4);
        }
#pragma unroll
        for (int p = 0; p < 4; ++p) {
            const int kk = (t >> 4) + 16 * p;
            const int c4 = (t & 15) * 4;
            rb[p] = *(const float4*)(Wb + (size_t)(kb + kk) * DG + n0 + c4);
        }
    };
    auto store_tile = [&](int buf) {
#pragma unroll
        for (int p = 0; p < 4; ++p) {
            const int idx = t + 256 * p;
            const int r = idx >> 4, q4 = idx & 15;
            unsigned short s4[4] = {f2bs(ra[p].x), f2bs(ra[p].y), f2bs(ra[p].z), f2bs(ra[p].w)};
            __builtin_memcpy(&As[buf][r][4 * q4], s4, 8);
        }
#pragma unroll
        for (int p = 0; p < 4; ++p) {
            const int kk = (t >> 4) + 16 * p;
            const int c4 = (t & 15) * 4;
            Bs[buf][c4 + 0][kk] = f2bs(rb[p].x);
            Bs[buf][c4 + 1][kk] = f2bs(rb[p].y);
            Bs[buf][c4 + 2][kk] = f2bs(rb[p].z);
            Bs[buf][c4 + 3][kk] = f2bs(rb[p].w);
        }
    };

    load_tile(0);
    store_tile(0);
    __syncthreads();
    for (int kc = 0; kc < 8; ++kc) {
        const int cur = kc & 1;
        if (kc < 7) load_tile(kc + 1);   // loads in flight across MFMA
#pragma unroll
        for (int ks = 0; ks < 2; ++ks) {
            const short8 bf = *(const short8*)&Bs[cur][w * 16 + l15][ks * 32 + quad * 8];
#pragma unroll
            for (int mi = 0; mi < 4; ++mi) {
                const short8 af = *(const short8*)&As[cur][mi * 16 + l15][ks * 32 + quad * 8];
                acc[mi] = __builtin_amdgcn_mfma_f32_16x16x32_bf16(af, bf, acc[mi], 0, 0, 0);
            }
        }
        if (kc < 7) store_tile(cur ^ 1);
        __syncthreads();   // single barrier per K-step
    }
    const int col = n0 + w * 16 + l15;
    const int h = col >> 8;
    const float as = aSrc[col], ad = aDst[col];
    if (isL) {
#pragma unroll
        for (int mi = 0; mi < 4; ++mi) {
            unsigned short s4[4];
#pragma unroll
            for (int r = 0; r < 4; ++r) s4[r] = f2bs(acc[mi][r]);
            __builtin_memcpy(&WhLbT[(size_t)col * NN + m0 + mi * 16 + quad * 4], s4, 8);
        }
#pragma unroll
        for (int mi = 0; mi < 4; ++mi)
#pragma unroll
            for (int r = 0; r < 4; ++r) {
                float sv = acc[mi][r] * as;
                float dv = acc[mi][r] * ad;
#pragma unroll
                for (int off = 1; off < 16; off <<= 1) {
                    sv += __shfl_xor(sv, off);
                    dv += __shfl_xor(dv, off);
                }
                if (l15 == 0) {
                    const int row = m0 + mi * 16 + quad * 4 + r;
                    srcLp[(p2 * NN + row) * HH + h] = sv;  // unique writer
                    dstLp[(p2 * NN + row) * HH + h] = dv;
                }
            }
    } else {
        float* Wv = WhVz + (size_t)z * BB * DG;
#pragma unroll
        for (int mi = 0; mi < 4; ++mi)
#pragma unroll
            for (int r = 0; r < 4; ++r)
                Wv[(size_t)(mi * 16 + quad * 4 + r) * DG + col] = acc[mi][r];
        const int pv = p2 * 4 + z;
#pragma unroll
        for (int mi = 0; mi < 4; ++mi)
#pragma unroll
            for (int r = 0; r < 4; ++r) {
                float sv = acc[mi][r] * as;
                float dv = acc[mi][r] * ad;
#pragma unroll
                for (int off = 1; off < 16; off <<= 1) {
                    sv += __shfl_xor(sv, off);
                    dv += __shfl_xor(dv, off);
                }
                if (l15 == 0) {
                    const int row = mi * 16 + quad * 4 + r;
                    srcVp[(pv * BB + row) * HH + h] = sv;  // unique writer
                    dstVp[(pv * BB + row) * HH + h] = dv;
                }
            }
    }
}

// ---------------- MFMA GAT v6 (best measured: grid 512, 4 it-tiles/block,
// max-identity softmax, in-loop abits loads, psl pool reduce).
__global__ void __launch_bounds__(512, 4) k_gat(const unsigned short* __restrict__ WhLbT,
                                                const float* __restrict__ WhVz,
                                                const float* __restrict__ srcLp,
                                                const float* __restrict__ dstLp,
                                                const float* __restrict__ srcVp,
                                                const float* __restrict__ dstVp,
                                                const unsigned short* __restrict__ abits,
                                                const float* __restrict__ pool_q,
                                                bf16* __restrict__ outb,
                                                float* __restrict__ ps_p) {
    const int bid = blockIdx.x;
    const int h = bid & 7;
    const int b = bid >> 3;
    const int t = threadIdx.x;
    const int w = t >> 6;
    const int lane = t & 63;
    const int l15 = lane & 15, quad = lane >> 4;

    __shared__ __align__(16) unsigned short Pl[64][PSTRIDE]; // 33.8 KB
    __shared__ __align__(16) float dls2[2 * NN];             // 2 KB
    __shared__ float slsA[NN], slsC[NN];                     // 2 KB
    __shared__ float inv[64];
    __shared__ float psl[8][64];                             // 2 KB

    // ---- phase 0 (hoisted: once per (b,h), covers all 4 it-tiles)
    if (t < NN) {
        float dl = 0.f, sl = 0.f;
#pragma unroll
        for (int p = 0; p < 4; ++p) {
            dl += dstLp[(p * NN + t) * HH + h];
            sl += srcLp[(p * NN + t) * HH + h];
        }
        dls2[2 * t]     = __expf(dl);
        dls2[2 * t + 1] = __expf(ALPHA * dl);
        float c = 0.f;
#pragma unroll
        for (int p = 0; p < 16; ++p)
            c += srcVp[(p * BB + b) * HH + h] + dstVp[(p * BB + b) * HH + h];
        const float u = c + sl;
        slsA[t] = __expf(u);
        slsC[t] = __expf(ALPHA * u);
    }
    const int n0 = w * 32;
    float wv[2] = {0.f, 0.f};
#pragma unroll
    for (int z = 0; z < 4; ++z)
#pragma unroll
        for (int ni = 0; ni < 2; ++ni)
            wv[ni] += WhVz[(size_t)z * BB * DG + (size_t)b * DG + h * FF + n0 + ni * 16 + l15];
    const float pqv0 = pool_q[h * FF + n0 + l15];
    const float pqv1 = pool_q[h * FF + n0 + 16 + l15];
    const unsigned short* wb = WhLbT + (size_t)(h * FF + n0 + l15) * NN + quad * 8;
    __syncthreads();

    for (int it = 0; it < 4; ++it) {
        const int i0 = it * 64;

        // ---- phase 1: masked exp via max identity (adj from 8KB bitmask)
        {
            const int g = lane >> 4, s = lane & 15;
#pragma unroll
            for (int rr = 0; rr < 2; ++rr) {
                const int iloc = w * 8 + rr * 4 + g;
                const int i = i0 + iloc;
                const unsigned int mb = abits[i * 16 + s];
                const float Ai = slsA[i], Ci = slsC[i];
                float pr[16];
                float sum = 0.f;
#pragma unroll
                for (int jj = 0; jj < 8; ++jj) {
                    const int j0 = 2 * s + 32 * jj;
                    const float4 bd = *(const float4*)&dls2[2 * j0];
                    float p0 = fmaxf(Ai * bd.x, Ci * bd.y);
                    float p1 = fmaxf(Ai * bd.z, Ci * bd.w);
                    p0 = (mb & (1u << (2 * jj)))     ? p0 : 0.f;
                    p1 = (mb & (1u << (2 * jj + 1))) ? p1 : 0.f;
                    pr[2 * jj] = p0; pr[2 * jj + 1] = p1;
                    sum += p0 + p1;
                }
#pragma unroll
                for (int off = 1; off < 16; off <<= 1) sum += __shfl_xor(sum, off);
                if (s == 0) inv[iloc] = 1.0f / sum;
#pragma unroll
                for (int jj = 0; jj < 8; ++jj) {
                    const unsigned int pk =
                        ((unsigned int)f2bs(pr[2 * jj + 1]) << 16) | f2bs(pr[2 * jj]);
                    *(unsigned int*)&Pl[iloc][2 * s + 32 * jj] = pk;
                }
            }
        }
        __syncthreads();

        // ---- phase 2: out[i0:+64, w*32:+32] = P~ @ WhL (mfma 16x16x32 bf16)
        f32x4 acc[4][2];
#pragma unroll
        for (int mi = 0; mi < 4; ++mi)
#pragma unroll
            for (int ni = 0; ni < 2; ++ni) acc[mi][ni] = (f32x4){0.f, 0.f, 0.f, 0.f};

        short8 bc0 = *(const short8*)(wb);
        short8 bc1 = *(const short8*)(wb + (size_t)16 * NN);
#pragma unroll
        for (int kc = 0; kc < 8; ++kc) {
            short8 bn0, bn1;
            if (kc < 7) {
                bn0 = *(const short8*)(wb + (kc + 1) * 32);
                bn1 = *(const short8*)(wb + (size_t)16 * NN + (kc + 1) * 32);
            }
            short8 a[4];
#pragma unroll
            for (int mi = 0; mi < 4; ++mi)
                a[mi] = *(const short8*)&Pl[mi * 16 + l15][kc * 32 + quad * 8];
#pragma unroll
            for (int mi = 0; mi < 4; ++mi)
                acc[mi][0] = __builtin_amdgcn_mfma_f32_16x16x32_bf16(a[mi], bc0, acc[mi][0], 0, 0, 0);
#pragma unroll
            for (int mi = 0; mi < 4; ++mi)
                acc[mi][1] = __builtin_amdgcn_mfma_f32_16x16x32_bf16(a[mi], bc1, acc[mi][1], 0, 0, 0);
            bc0 = bn0; bc1 = bn1;
        }

        // ---- register epilogue: normalize + WhV, ELU, bf16 store + pool dot
#pragma unroll
        for (int mi = 0; mi < 4; ++mi)
#pragma unroll
            for (int r = 0; r < 4; ++r) {
                const int row = mi * 16 + quad * 4 + r;
                const float ivr = inv[row];
                bf16* orow = outb + ((size_t)(b * NN + i0 + row)) * DG + h * FF + n0;
                float x0 = fmaf(acc[mi][0][r], ivr, wv[0]);
                float x1 = fmaf(acc[mi][1][r], ivr, wv[1]);
                x0 = x0 > 0.f ? x0 : (__expf(x0) - 1.0f);
                x1 = x1 > 0.f ? x1 : (__expf(x1) - 1.0f);
                orow[l15]      = __float2bfloat16(x0);
                orow[16 + l15] = __float2bfloat16(x1);
                float dot = fmaf(x0, pqv0, x1 * pqv1);
#pragma unroll
                for (int off = 1; off < 16; off <<= 1) dot += __shfl_xor(dot, off);
                if (l15 == 0) psl[w][row] = dot;
            }
        __syncthreads();  // psl ready; Pl consumers done (safe to rewrite next it)
        if (t < 64) {
            float s = 0.f;
#pragma unroll
            for (int ww = 0; ww < 8; ++ww) s += psl[ww][t];
            ps_p[((size_t)h * BB + b) * NN + i0 + t] = s;
        }
        // next-it psl/Pl writes are gated by the phase-1 barrier, which the
        // reducing wave reaches only after this store.
    }
}

// ---------------- k_pool v3 (round-5): n-split partials, full-GPU streaming.
// grid (4 dt, 64 b, 4 ns), 256 thr; thread owns TWO consecutive d cols,
// n-range 64 per block -> 1024 blocks. Partials summed in k_mgemm.
__global__ void __launch_bounds__(256) k_pool(const bf16* __restrict__ outb,
                                              const float* __restrict__ ps_p,
                                              float* __restrict__ pooled_p,
                                              const float* __restrict__ fcb,
                                              float* __restrict__ out) {
    const int dt = blockIdx.x;  // 0..3
    const int b  = blockIdx.y;  // 0..63
    const int ns = blockIdx.z;  // 0..3
    const int t  = threadIdx.x;
    if (dt == 0 && ns == 0) {
        out[b * DE + t]       = fcb[t];
        out[b * DE + 256 + t] = fcb[256 + t];
    }
    __shared__ float wsm[NN];
    __shared__ float redm[4];
    __shared__ float reds[4];
    float v = 0.f;
#pragma unroll
    for (int s = 0; s < 8; ++s)
        v += ps_p[((size_t)s * BB + b) * NN + t];
    float m = v;
#pragma unroll
    for (int off = 32; off; off >>= 1) m = fmaxf(m, __shfl_xor(m, off));
    if ((t & 63) == 0) redm[t >> 6] = m;
    __syncthreads();
    m = fmaxf(fmaxf(redm[0], redm[1]), fmaxf(redm[2], redm[3]));
    const float e = __expf(v - m);
    float s = e;
#pragma unroll
    for (int off = 32; off; off >>= 1) s += __shfl_xor(s, off);
    if ((t & 63) == 0) reds[t >> 6] = s;
    __syncthreads();
    s = reds[0] + reds[1] + reds[2] + reds[3];
    wsm[t] = e / s;
    __syncthreads();
    const int d0 = dt * 512 + t * 2;
    const int nb = ns * 64;
    float a0 = 0.f, a1 = 0.f;
    const bf16* base = outb + (size_t)b * NN * DG + d0;
#pragma unroll 8
    for (int n = 0; n < 64; ++n) {
        unsigned int q = *(const unsigned int*)(base + (size_t)(nb + n) * DG);
        const float wn = wsm[nb + n];
        a0 = fmaf(wn, bs2f((unsigned short)(q & 0xffff)), a0);
        a1 = fmaf(wn, bs2f((unsigned short)(q >> 16)), a1);
    }
    float2 r2 = {a0, a1};
    *(float2*)(pooled_p + ((size_t)(ns * BB + b)) * DG + d0) = r2;
}

// ---------------- fc GEMM: A = sum of NSPLIT pooled partials; atomic ksplit
__global__ void __launch_bounds__(256) k_mgemm(const float* __restrict__ Ap,
                                               const float* __restrict__ W, int ldw,
                                               float* __restrict__ C, int ldc,
                                               int kSlice, int kIters) {
    __shared__ unsigned short As[32][72];
    __shared__ unsigned short Bs[64][72];
    const int t = threadIdx.x;
    const int w = t >> 6;
    const int lane = t & 63;
    const int l15 = lane & 15, quad = lane >> 4;
    const int n0 = blockIdx.x * 64;
    const int m0 = blockIdx.y * 32;
    const int kb0 = blockIdx.z * kSlice;
    f32x4 acc[2];
    acc[0] = (f32x4){0.f, 0.f, 0.f, 0.f};
    acc[1] = (f32x4){0.f, 0.f, 0.f, 0.f};
    for (int kc = 0; kc < kIters; ++kc) {
        const int kb = kb0 + kc * 64;
#pragma unroll
        for (int p = 0; p < 2; ++p) {
            const int idx = t + 256 * p;
            const int r = idx >> 4, q4 = idx & 15;
            const float* ap = Ap + (size_t)(m0 + r) * DG + kb + 4 * q4;
            const float4 v0 = *(const float4*)(ap);
            const float4 v1 = *(const float4*)(ap + (size_t)BB * DG);
            const float4 v2 = *(const float4*)(ap + (size_t)2 * BB * DG);
            const float4 v3 = *(const float4*)(ap + (size_t)3 * BB * DG);
            const float vx = v0.x + v1.x + v2.x + v3.x;
            const float vy = v0.y + v1.y + v2.y + v3.y;
            const float vz = v0.z + v1.z + v2.z + v3.z;
            const float vw = v0.w + v1.w + v2.w + v3.w;
            unsigned short s4[4] = {f2bs(vx), f2bs(vy), f2bs(vz), f2bs(vw)};
            __builtin_memcpy(&As[r][4 * q4], s4, 8);
        }
#pragma unroll
        for (int p = 0; p < 4; ++p) {
            const int kk = (t >> 4) + 16 * p;
            const int c4 = (t & 15) * 4;
            const float4 v = *(const float4*)(W + (size_t)(kb + kk) * ldw + n0 + c4);
            Bs[c4 + 0][kk] = f2bs(v.x);
            Bs[c4 + 1][kk] = f2bs(v.y);
            Bs[c4 + 2][kk] = f2bs(v.z);
            Bs[c4 + 3][kk] = f2bs(v.w);
        }
        __syncthreads();
#pragma unroll
        for (int ks = 0; ks < 2; ++ks) {
            const short8 bf = *(const short8*)&Bs[w * 16 + l15][ks * 32 + quad * 8];
#pragma unroll
            for (int mi = 0; mi < 2; ++mi) {
                const short8 af = *(const short8*)&As[mi * 16 + l15][ks * 32 + quad * 8];
                acc[mi] = __builtin_amdgcn_mfma_f32_16x16x32_bf16(af, bf, acc[mi], 0, 0, 0);
            }
        }
        __syncthreads();
    }
    const int col = n0 + w * 16 + l15;
#pragma unroll
    for (int mi = 0; mi < 2; ++mi)
#pragma unroll
        for (int r = 0; r < 4; ++r)
            atomicAdd(&C[(size_t)(m0 + mi * 16 + quad * 4 + r) * ldc + col], acc[mi][r]);
}

extern "C" void kernel_launch(void* const* d_in, const int* in_sizes, int n_in,
                              void* d_out, int out_size, void* d_ws, size_t ws_size,
                              hipStream_t stream) {
    (void)in_sizes; (void)n_in; (void)out_size; (void)ws_size;
    const float* visual = (const float*)d_in[0];
    const float* labels = (const float*)d_in[1];
    const float* adj    = (const float*)d_in[2];
    const float* Wg     = (const float*)d_in[3];
    const float* a_src  = (const float*)d_in[4];
    const float* a_dst  = (const float*)d_in[5];
    const float* pool_q = (const float*)d_in[6];
    const float* fcW    = (const float*)d_in[7];
    const float* fcb    = (const float*)d_in[8];
    float* out = (float*)d_out;

    float* ws_f     = (float*)d_ws;
    float* WhVz     = ws_f;                       // 4*64*2048
    float* srcLp    = WhVz + 4 * BB * DG;         // 4*256*8
    float* dstLp    = srcLp + 4 * NN * HH;        // 4*256*8
    float* srcVp    = dstLp + 4 * NN * HH;        // 16*64*8
    float* dstVp    = srcVp + 16 * BB * HH;       // 16*64*8
    float* ps_p     = dstVp + 16 * BB * HH;       // 8*64*256 (h-slices only)
    float* pooled_p = ps_p + 8 * BB * NN;         // 4*64*2048 (ns partials)
    bf16*  outb     = (bf16*)(pooled_p + NSPLIT * BB * DG);  // 64*256*2048 bf16
    unsigned short* WhLbT = (unsigned short*)(outb + (size_t)BB * NN * DG); // 2048*256
    unsigned short* abits = WhLbT + (size_t)DG * NN;  // 256*16 ushort (8KB)

    k_wh<<<dim3(DG / 64, 9), 256, 0, stream>>>(labels, visual, Wg, WhLbT, WhVz,
                                               a_src, a_dst, srcLp, dstLp, srcVp, dstVp,
                                               adj, abits);

    k_gat<<<BB * HH, 512, 0, stream>>>(WhLbT, WhVz, srcLp, dstLp, srcVp, dstVp,
                                       abits, pool_q, outb, ps_p);

    k_pool<<<dim3(4, BB, NSPLIT), 256, 0, stream>>>(outb, ps_p, pooled_p, fcb, out);

    k_mgemm<<<dim3(DE / 64, BB / 32, 16), 256, 0, stream>>>(
        pooled_p, fcW, DE, out, DE, 128, 2);
}